// Round 1
// baseline (1052.387 us; speedup 1.0000x reference)
//
#include <hip/hip_runtime.h>
#include <hip/hip_bf16.h>
#include <stdint.h>

#define B_ROWS 8192
#define K_DIM  2048
#define N_DIM  3072
#define S_NUM  8

#define BM 128
#define BN 128
#define BK 32
#define LDA 40   // BK + 8 pad (elements); row stride 80 B = 16B-aligned, bank stride 20
#define LDB 40

typedef __bf16 bf16x8 __attribute__((ext_vector_type(8)));
typedef float  f32x4  __attribute__((ext_vector_type(4)));
typedef unsigned short u16x8 __attribute__((ext_vector_type(8)));

// fp32 -> bf16 round-to-nearest-even (inputs are finite; no NaN path needed)
__device__ __forceinline__ unsigned short f2bf(float f) {
    unsigned int u = __builtin_bit_cast(unsigned int, f);
    u += 0x7FFFu + ((u >> 16) & 1u);
    return (unsigned short)(u >> 16);
}

__global__ void zero_cnt_kernel(int* __restrict__ cnt) {
    if (threadIdx.x < S_NUM) cnt[threadIdx.x] = 0;
}

__global__ void bucket_kernel(const int* __restrict__ ids,
                              int* __restrict__ cnt,
                              unsigned short* __restrict__ perm) {
    int b = blockIdx.x * blockDim.x + threadIdx.x;
    if (b < B_ROWS) {
        int s = ids[b];
        int pos = atomicAdd(&cnt[s], 1);
        perm[s * B_ROWS + pos] = (unsigned short)b;
    }
}

__global__ __launch_bounds__(256, 2)
void subject_gemm_kernel(const float* __restrict__ x,
                         const float* __restrict__ w,
                         const float* __restrict__ bias,
                         const int* __restrict__ cnt,
                         const unsigned short* __restrict__ perm,
                         float* __restrict__ out) {
    const int s    = blockIdx.z;
    const int c    = cnt[s];
    const int row0 = blockIdx.x * BM;
    if (row0 >= c) return;                 // tile beyond this subject's rows
    const int rows = min(BM, c - row0);
    const int n0   = blockIdx.y * BN;

    __shared__ __align__(16) unsigned short sA[BM * LDA];  // [m][k], k contiguous
    __shared__ __align__(16) unsigned short sB[BN * LDB];  // [n][k], k contiguous
    __shared__ int prow[BM];

    const int tid = threadIdx.x;
    if (tid < BM) {
        int rr = (tid < rows) ? tid : (rows - 1);  // duplicate last valid row; stores guarded
        prow[tid] = (int)perm[s * B_ROWS + row0 + rr];
    }
    __syncthreads();

    // A staging: thread -> (row = tid>>1, k-half = (tid&1)*16), 4x float4 loads
    const int ar = tid >> 1;
    const int ah = tid & 1;
    const float* xp = x + (size_t)prow[ar] * K_DIM + ah * 16;

    // B staging: thread -> (n = tid&127, k-half = (tid>>7)*16), 16 coalesced dword loads
    const int bn  = tid & 127;
    const int bk2 = tid >> 7;
    const float* wp = w + (size_t)s * ((size_t)K_DIM * N_DIM)
                        + (size_t)(bk2 * 16) * N_DIM + (n0 + bn);

    const int lane = tid & 63;
    const int wid  = tid >> 6;
    const int wm   = (wid >> 1) * 64;   // 2x2 wave grid, 64x64 per wave
    const int wn   = (wid & 1) * 64;
    const int l15  = lane & 15;
    const int quad = lane >> 4;

    f32x4 acc[4][4] = {};

    for (int ks = 0; ks < K_DIM / BK; ++ks) {
        // ---- global loads (fp32) ----
        const float* xq = xp + ks * BK;
        f32x4 a0 = *(const f32x4*)(xq + 0);
        f32x4 a1 = *(const f32x4*)(xq + 4);
        f32x4 a2 = *(const f32x4*)(xq + 8);
        f32x4 a3 = *(const f32x4*)(xq + 12);

        const float* wq = wp + (size_t)(ks * BK) * N_DIM;
        float bv[16];
        #pragma unroll
        for (int i = 0; i < 16; ++i) bv[i] = wq[(size_t)i * N_DIM];

        // ---- convert to bf16, pack ----
        u16x8 pa0, pa1, pb0, pb1;
        #pragma unroll
        for (int i = 0; i < 4; ++i) { pa0[i] = f2bf(a0[i]); pa0[i + 4] = f2bf(a1[i]); }
        #pragma unroll
        for (int i = 0; i < 4; ++i) { pa1[i] = f2bf(a2[i]); pa1[i + 4] = f2bf(a3[i]); }
        #pragma unroll
        for (int i = 0; i < 8; ++i) { pb0[i] = f2bf(bv[i]); pb1[i] = f2bf(bv[i + 8]); }

        // ---- LDS stores (ds_write_b128, 16B aligned) ----
        *(u16x8*)&sA[ar * LDA + ah * 16 + 0] = pa0;
        *(u16x8*)&sA[ar * LDA + ah * 16 + 8] = pa1;
        *(u16x8*)&sB[bn * LDB + bk2 * 16 + 0] = pb0;   // transposed: [n][k]
        *(u16x8*)&sB[bn * LDB + bk2 * 16 + 8] = pb1;

        __syncthreads();

        // ---- fragments (ds_read_b128) + MFMA ----
        bf16x8 af[4], bfr[4];
        #pragma unroll
        for (int mt = 0; mt < 4; ++mt)
            af[mt] = *(const bf16x8*)&sA[(wm + mt * 16 + l15) * LDA + quad * 8];
        #pragma unroll
        for (int nt = 0; nt < 4; ++nt)
            bfr[nt] = *(const bf16x8*)&sB[(wn + nt * 16 + l15) * LDB + quad * 8];

        #pragma unroll
        for (int mt = 0; mt < 4; ++mt)
            #pragma unroll
            for (int nt = 0; nt < 4; ++nt)
                acc[mt][nt] = __builtin_amdgcn_mfma_f32_16x16x32_bf16(
                    af[mt], bfr[nt], acc[mt][nt], 0, 0, 0);

        __syncthreads();
    }

    // ---- epilogue: bias add + scattered row store ----
    float bvals[4];
    #pragma unroll
    for (int nt = 0; nt < 4; ++nt)
        bvals[nt] = bias[s * N_DIM + n0 + wn + nt * 16 + l15];

    #pragma unroll
    for (int mt = 0; mt < 4; ++mt) {
        #pragma unroll
        for (int r = 0; r < 4; ++r) {
            int rl = wm + mt * 16 + quad * 4 + r;   // C/D: col=lane&15, row=quad*4+reg
            if (rl < rows) {
                float* op = out + (size_t)prow[rl] * N_DIM + n0 + wn + l15;
                #pragma unroll
                for (int nt = 0; nt < 4; ++nt)
                    op[nt * 16] = acc[mt][nt][r] + bvals[nt];
            }
        }
    }
}

extern "C" void kernel_launch(void* const* d_in, const int* in_sizes, int n_in,
                              void* d_out, int out_size, void* d_ws, size_t ws_size,
                              hipStream_t stream) {
    const float* x    = (const float*)d_in[0];
    const int*   sid  = (const int*)d_in[1];
    const float* w    = (const float*)d_in[2];
    const float* bias = (const float*)d_in[3];
    float* out = (float*)d_out;

    // ws layout: [0,32): int cnt[8]; [64, 64+2*S*B): uint16 perm buckets (~131 KB)
    int* cnt = (int*)d_ws;
    unsigned short* perm = (unsigned short*)((char*)d_ws + 64);

    hipLaunchKernelGGL(zero_cnt_kernel, dim3(1), dim3(64), 0, stream, cnt);
    hipLaunchKernelGGL(bucket_kernel, dim3(B_ROWS / 256), dim3(256), 0, stream,
                       sid, cnt, perm);
    dim3 grid(B_ROWS / BM, N_DIM / BN, S_NUM);
    hipLaunchKernelGGL(subject_gemm_kernel, grid, dim3(256), 0, stream,
                       x, w, bias, cnt, perm, out);
}

// Round 2
// 659.673 us; speedup vs baseline: 1.5953x; 1.5953x over previous
//
#include <hip/hip_runtime.h>
#include <hip/hip_bf16.h>
#include <stdint.h>

#define B_ROWS 8192
#define K_DIM  2048
#define N_DIM  3072
#define S_NUM  8

#define BM 128
#define BN 128
#define BK 32
#define LDA 40   // BK + 8 pad (bf16 elems); row stride 80 B (16B-aligned)
#define LDB 40
#define NK (K_DIM / BK)
#define MAX_TILES 72  // sum_s ceil(c_s/128) <= 64 + 8

typedef __bf16 bf16x8 __attribute__((ext_vector_type(8)));
typedef float  f32x4  __attribute__((ext_vector_type(4)));
typedef unsigned int u32x4 __attribute__((ext_vector_type(4)));

// pack two fp32 -> two bf16 (RNE). gfx950 has v_cvt_pk_bf16_f32.
__device__ __forceinline__ unsigned int f2bf_pk(float lo, float hi) {
#if __has_builtin(__builtin_amdgcn_cvt_pk_bf16_f32)
    typedef __bf16 bf16x2_t __attribute__((ext_vector_type(2)));
    bf16x2_t v = __builtin_amdgcn_cvt_pk_bf16_f32(lo, hi);
    return __builtin_bit_cast(unsigned int, v);
#else
    unsigned int a = __builtin_bit_cast(unsigned int, lo);
    unsigned int b = __builtin_bit_cast(unsigned int, hi);
    a += 0x7FFFu + ((a >> 16) & 1u);
    b += 0x7FFFu + ((b >> 16) & 1u);
    return (a >> 16) | (b & 0xFFFF0000u);
#endif
}

__global__ void zero_cnt_kernel(int* __restrict__ cnt) {
    if (threadIdx.x < S_NUM) cnt[threadIdx.x] = 0;
}

// ballot-based bucketing: one global atomic per (wave, subject) instead of per row
__global__ void bucket_kernel(const int* __restrict__ ids,
                              int* __restrict__ cnt,
                              unsigned short* __restrict__ perm) {
    const int b = blockIdx.x * blockDim.x + threadIdx.x;
    const int lane = threadIdx.x & 63;
    const int s = ids[b];
    #pragma unroll
    for (int sub = 0; sub < S_NUM; ++sub) {
        unsigned long long m = __ballot(s == sub);
        if (s == sub) {
            int prefix = __popcll(m & ((1ull << lane) - 1ull));
            int leader = __ffsll((unsigned long long)m) - 1;
            int base = 0;
            if (lane == leader) base = atomicAdd(&cnt[sub], __popcll(m));
            base = __shfl(base, leader);
            perm[sub * B_ROWS + base + prefix] = (unsigned short)b;
        }
    }
}

// build exact tile list: (subject, row0) per m-tile
__global__ void plan_kernel(const int* __restrict__ cnt,
                            int* __restrict__ tile_s, int* __restrict__ tile_m) {
    if (threadIdx.x == 0 && blockIdx.x == 0) {
        int t = 0;
        for (int s = 0; s < S_NUM; ++s)
            for (int m0 = 0; m0 < cnt[s]; m0 += BM) {
                tile_s[t] = s; tile_m[t] = m0; ++t;
            }
        for (; t < MAX_TILES; ++t) { tile_s[t] = -1; tile_m[t] = 0; }
    }
}

__global__ __launch_bounds__(256, 3)
void subject_gemm_kernel(const float* __restrict__ x,
                         const float* __restrict__ w,
                         const float* __restrict__ bias,
                         const int* __restrict__ cnt,
                         const int* __restrict__ tile_s,
                         const int* __restrict__ tile_m,
                         const unsigned short* __restrict__ perm,
                         float* __restrict__ out) {
    const int s = tile_s[blockIdx.x];
    if (s < 0) return;
    const int row0 = tile_m[blockIdx.x];
    const int rows = min(BM, cnt[s] - row0);
    const int n0   = blockIdx.y * BN;

    __shared__ __align__(16) unsigned short sA[BM * LDA];  // [m][k]
    __shared__ __align__(16) unsigned short sB[BN * LDB];  // [n][k] (transposed)
    __shared__ int prow[BM];

    const int tid = threadIdx.x;
    if (tid < BM) {
        int rr = (tid < rows) ? tid : (rows - 1);  // dup last valid row; stores guarded
        prow[tid] = (int)perm[s * B_ROWS + row0 + rr];
    }
    __syncthreads();

    // A staging: thread -> (row = tid>>1, k-half = (tid&1)*16)
    const int ar = tid >> 1;
    const int ah = tid & 1;
    const float* xp = x + (size_t)prow[ar] * K_DIM + ah * 16;

    // B staging: thread -> (n = tid&127, k-half = (tid>>7)*16), coalesced dwords
    const int bn  = tid & 127;
    const int bk2 = tid >> 7;
    const float* wp = w + (size_t)s * ((size_t)K_DIM * N_DIM)
                        + (size_t)(bk2 * 16) * N_DIM + (n0 + bn);

    const int lane = tid & 63;
    const int wid  = tid >> 6;
    const int wm   = (wid >> 1) * 64;
    const int wn   = (wid & 1) * 64;
    const int l15  = lane & 15;
    const int quad = lane >> 4;

    f32x4 acc[4][4] = {};
    f32x4 a0, a1, a2, a3;
    float bv[16];

    // ---- prologue: load tile 0 into registers ----
    {
        const float* xq = xp;
        a0 = *(const f32x4*)(xq + 0);  a1 = *(const f32x4*)(xq + 4);
        a2 = *(const f32x4*)(xq + 8);  a3 = *(const f32x4*)(xq + 12);
        const float* wq = wp;
        #pragma unroll
        for (int i = 0; i < 16; ++i) bv[i] = wq[(size_t)i * N_DIM];
    }

    for (int ks = 0; ks < NK; ++ks) {
        // convert current tile (register-only, overlaps prior iter's MFMA tail)
        u32x4 pa0 = { f2bf_pk(a0[0],a0[1]), f2bf_pk(a0[2],a0[3]),
                      f2bf_pk(a1[0],a1[1]), f2bf_pk(a1[2],a1[3]) };
        u32x4 pa1 = { f2bf_pk(a2[0],a2[1]), f2bf_pk(a2[2],a2[3]),
                      f2bf_pk(a3[0],a3[1]), f2bf_pk(a3[2],a3[3]) };
        u32x4 pb0 = { f2bf_pk(bv[0],bv[1]),   f2bf_pk(bv[2],bv[3]),
                      f2bf_pk(bv[4],bv[5]),   f2bf_pk(bv[6],bv[7]) };
        u32x4 pb1 = { f2bf_pk(bv[8],bv[9]),   f2bf_pk(bv[10],bv[11]),
                      f2bf_pk(bv[12],bv[13]), f2bf_pk(bv[14],bv[15]) };

        __syncthreads();   // prior iteration's ds_reads complete
        *(u32x4*)&sA[ar * LDA + ah * 16 + 0] = pa0;
        *(u32x4*)&sA[ar * LDA + ah * 16 + 8] = pa1;
        *(u32x4*)&sB[bn * LDB + bk2 * 16 + 0] = pb0;
        *(u32x4*)&sB[bn * LDB + bk2 * 16 + 8] = pb1;
        __syncthreads();

        // prefetch next tile's globals — latency overlaps ds_read + MFMA below
        if (ks + 1 < NK) {
            const float* xq = xp + (ks + 1) * BK;
            a0 = *(const f32x4*)(xq + 0);  a1 = *(const f32x4*)(xq + 4);
            a2 = *(const f32x4*)(xq + 8);  a3 = *(const f32x4*)(xq + 12);
            const float* wq = wp + (size_t)((ks + 1) * BK) * N_DIM;
            #pragma unroll
            for (int i = 0; i < 16; ++i) bv[i] = wq[(size_t)i * N_DIM];
        }

        bf16x8 af[4], bfr[4];
        #pragma unroll
        for (int mt = 0; mt < 4; ++mt)
            af[mt] = *(const bf16x8*)&sA[(wm + mt * 16 + l15) * LDA + quad * 8];
        #pragma unroll
        for (int nt = 0; nt < 4; ++nt)
            bfr[nt] = *(const bf16x8*)&sB[(wn + nt * 16 + l15) * LDB + quad * 8];

        #pragma unroll
        for (int mt = 0; mt < 4; ++mt)
            #pragma unroll
            for (int nt = 0; nt < 4; ++nt)
                acc[mt][nt] = __builtin_amdgcn_mfma_f32_16x16x32_bf16(
                    af[mt], bfr[nt], acc[mt][nt], 0, 0, 0);
    }

    // ---- epilogue: bias add + scattered row store ----
    float bvals[4];
    #pragma unroll
    for (int nt = 0; nt < 4; ++nt)
        bvals[nt] = bias[s * N_DIM + n0 + wn + nt * 16 + l15];

    #pragma unroll
    for (int mt = 0; mt < 4; ++mt) {
        #pragma unroll
        for (int r = 0; r < 4; ++r) {
            int rl = wm + mt * 16 + quad * 4 + r;   // C/D: col=lane&15, row=quad*4+reg
            if (rl < rows) {
                float* op = out + (size_t)prow[rl] * N_DIM + n0 + wn + l15;
                #pragma unroll
                for (int nt = 0; nt < 4; ++nt)
                    op[nt * 16] = acc[mt][nt][r] + bvals[nt];
            }
        }
    }
}

extern "C" void kernel_launch(void* const* d_in, const int* in_sizes, int n_in,
                              void* d_out, int out_size, void* d_ws, size_t ws_size,
                              hipStream_t stream) {
    const float* x    = (const float*)d_in[0];
    const int*   sid  = (const int*)d_in[1];
    const float* w    = (const float*)d_in[2];
    const float* bias = (const float*)d_in[3];
    float* out = (float*)d_out;

    // ws layout: [0,32) cnt; [64,352) tile_s; [448,736) tile_m; [1024,+128K) perm
    int* cnt    = (int*)d_ws;
    int* tile_s = (int*)((char*)d_ws + 64);
    int* tile_m = (int*)((char*)d_ws + 448);
    unsigned short* perm = (unsigned short*)((char*)d_ws + 1024);

    hipLaunchKernelGGL(zero_cnt_kernel, dim3(1), dim3(64), 0, stream, cnt);
    hipLaunchKernelGGL(bucket_kernel, dim3(B_ROWS / 256), dim3(256), 0, stream,
                       sid, cnt, perm);
    hipLaunchKernelGGL(plan_kernel, dim3(1), dim3(64), 0, stream,
                       cnt, tile_s, tile_m);
    dim3 grid(MAX_TILES, N_DIM / BN);
    hipLaunchKernelGGL(subject_gemm_kernel, grid, dim3(256), 0, stream,
                       x, w, bias, cnt, tile_s, tile_m, perm, out);
}

// Round 3
// 557.601 us; speedup vs baseline: 1.8873x; 1.1831x over previous
//
#include <hip/hip_runtime.h>
#include <hip/hip_bf16.h>
#include <stdint.h>

#define B_ROWS 8192
#define K_DIM  2048
#define N_DIM  3072
#define S_NUM  8

#define BM 128
#define BN 128
#define BK 32
#define NK (K_DIM / BK)
#define MAX_TILES 72

// fallback-path LDS strides (padded)
#define LDA 40
#define LDB 40

typedef __bf16 bf16x8 __attribute__((ext_vector_type(8)));
typedef float  f32x4  __attribute__((ext_vector_type(4)));
typedef unsigned int   u32x4 __attribute__((ext_vector_type(4)));
typedef unsigned short u16x8 __attribute__((ext_vector_type(8)));

// ---- workspace layout (fast path) ----
#define WS_CNT    0
#define WS_OFFS   256
#define WS_TILES  512        // tile_s[72]
#define WS_TILEM  1024       // tile_m[72]
#define WS_RANK   4096       // int[8192]  = 32 KB
#define WS_PERM   36864      // u16[65536] = 128 KB
#define WS_XPERM  262144     // bf16 (8192+128)*2048 = 34,078,720 B
#define WS_WT     34603008   // bf16 8*3072*2048     = 100,663,296 B
#define WS_NEED   135266304ULL

__device__ __forceinline__ unsigned int f2bf_pk(float lo, float hi) {
#if __has_builtin(__builtin_amdgcn_cvt_pk_bf16_f32)
    typedef __bf16 bf16x2_t __attribute__((ext_vector_type(2)));
    bf16x2_t v = __builtin_amdgcn_cvt_pk_bf16_f32(lo, hi);
    return __builtin_bit_cast(unsigned int, v);
#else
    unsigned int a = __builtin_bit_cast(unsigned int, lo);
    unsigned int b = __builtin_bit_cast(unsigned int, hi);
    a += 0x7FFFu + ((a >> 16) & 1u);
    b += 0x7FFFu + ((b >> 16) & 1u);
    return (a >> 16) | (b & 0xFFFF0000u);
#endif
}

__device__ __forceinline__ void gl_lds16(const void* g, void* l) {
    __builtin_amdgcn_global_load_lds(
        (const __attribute__((address_space(1))) void*)g,
        (__attribute__((address_space(3))) void*)l, 16, 0, 0);
}

__global__ void zero_cnt_kernel(int* __restrict__ cnt) {
    if (threadIdx.x < S_NUM) cnt[threadIdx.x] = 0;
}

// ballot bucketing; also records rank (position within subject) per row
__global__ void bucket_kernel(const int* __restrict__ ids,
                              int* __restrict__ cnt,
                              unsigned short* __restrict__ perm,
                              int* __restrict__ rank) {
    const int b = blockIdx.x * blockDim.x + threadIdx.x;
    const int lane = threadIdx.x & 63;
    const int s = ids[b];
    #pragma unroll
    for (int sub = 0; sub < S_NUM; ++sub) {
        unsigned long long m = __ballot(s == sub);
        if (s == sub) {
            int prefix = __popcll(m & ((1ull << lane) - 1ull));
            int leader = __ffsll((unsigned long long)m) - 1;
            int base = 0;
            if (lane == leader) base = atomicAdd(&cnt[sub], __popcll(m));
            base = __shfl(base, leader);
            perm[sub * B_ROWS + base + prefix] = (unsigned short)b;
            rank[b] = base + prefix;
        }
    }
}

// exact tile list + exclusive prefix offsets
__global__ void plan_kernel(const int* __restrict__ cnt, int* __restrict__ offs,
                            int* __restrict__ tile_s, int* __restrict__ tile_m) {
    if (threadIdx.x == 0 && blockIdx.x == 0) {
        int t = 0, o = 0;
        for (int s = 0; s < S_NUM; ++s) {
            offs[s] = o; o += cnt[s];
            for (int m0 = 0; m0 < cnt[s]; m0 += BM) {
                tile_s[t] = s; tile_m[t] = m0; ++t;
            }
        }
        for (; t < MAX_TILES; ++t) { tile_s[t] = -1; tile_m[t] = 0; }
    }
}

// x fp32 -> bf16, permuted into bucket-concatenated order. 1 block per row.
__global__ void convert_x_kernel(const float* __restrict__ x,
                                 const int* __restrict__ ids,
                                 const int* __restrict__ rank,
                                 const int* __restrict__ offs,
                                 unsigned short* __restrict__ xq) {
    const int b = blockIdx.x;
    const int dst = offs[ids[b]] + rank[b];
    const float* src = x + (size_t)b * K_DIM + threadIdx.x * 8;
    f32x4 v0 = *(const f32x4*)(src + 0);
    f32x4 v1 = *(const f32x4*)(src + 4);
    u32x4 p = { f2bf_pk(v0[0], v0[1]), f2bf_pk(v0[2], v0[3]),
                f2bf_pk(v1[0], v1[1]), f2bf_pk(v1[2], v1[3]) };
    *(u32x4*)(xq + (size_t)dst * K_DIM + threadIdx.x * 8) = p;
}

// w fp32 [s][k][n] -> bf16 [s][n][k] via LDS-tiled transpose (128n x 32k tiles)
#define TW_LD 136   // 128 + 8 pad (u16), row stride 272 B (16B-aligned)
__global__ void convert_w_kernel(const float* __restrict__ w,
                                 unsigned short* __restrict__ wt) {
    const int kt = blockIdx.x, nt = blockIdx.y, s = blockIdx.z;
    __shared__ __align__(16) unsigned short lds[32 * TW_LD];

    const int tid = threadIdx.x;
    {   // read 32k x 128n fp32, coalesced; convert; store LDS [k][n]
        const int k = tid >> 3;          // 0..31
        const int nseg = tid & 7;        // 16 n each
        const float* src = w + ((size_t)s * K_DIM + kt * 32 + k) * N_DIM
                             + nt * 128 + nseg * 16;
        f32x4 v0 = *(const f32x4*)(src + 0);
        f32x4 v1 = *(const f32x4*)(src + 4);
        f32x4 v2 = *(const f32x4*)(src + 8);
        f32x4 v3 = *(const f32x4*)(src + 12);
        u32x4 p0 = { f2bf_pk(v0[0], v0[1]), f2bf_pk(v0[2], v0[3]),
                     f2bf_pk(v1[0], v1[1]), f2bf_pk(v1[2], v1[3]) };
        u32x4 p1 = { f2bf_pk(v2[0], v2[1]), f2bf_pk(v2[2], v2[3]),
                     f2bf_pk(v3[0], v3[1]), f2bf_pk(v3[2], v3[3]) };
        *(u32x4*)&lds[k * TW_LD + nseg * 16 + 0] = p0;
        *(u32x4*)&lds[k * TW_LD + nseg * 16 + 8] = p1;
    }
    __syncthreads();
    {   // write [n][k]: thread -> (n = tid>>1, half = tid&1 covering 16 k)
        const int n = tid >> 1;
        const int half = tid & 1;
        u16x8 o0, o1;
        #pragma unroll
        for (int j = 0; j < 8; ++j) {
            o0[j] = lds[(half * 16 + j) * TW_LD + n];
            o1[j] = lds[(half * 16 + 8 + j) * TW_LD + n];
        }
        unsigned short* dst = wt + ((size_t)s * N_DIM + nt * 128 + n) * K_DIM
                                 + kt * 32 + half * 16;
        *(u16x8*)(dst + 0) = o0;
        *(u16x8*)(dst + 8) = o1;
    }
}

// ---- fast GEMM: pure bf16, global_load_lds staging (m97 structure) ----
__global__ __launch_bounds__(256, 4)
void gemm_bf16_kernel(const unsigned short* __restrict__ xq,
                      const unsigned short* __restrict__ wt,
                      const float* __restrict__ bias,
                      const int* __restrict__ cnt,
                      const int* __restrict__ offs,
                      const int* __restrict__ tile_s,
                      const int* __restrict__ tile_m,
                      const unsigned short* __restrict__ perm,
                      float* __restrict__ out) {
    const int s = tile_s[blockIdx.x];
    if (s < 0) return;
    const int row0 = tile_m[blockIdx.x];
    const int rows = min(BM, cnt[s] - row0);
    const int n0   = blockIdx.y * BN;

    __shared__ __align__(16) unsigned short sA[BM * BK];  // [m][k], 8 KB, no pad
    __shared__ __align__(16) unsigned short sB[BN * BK];  // [n][k], 8 KB, no pad
    __shared__ int prow[BM];

    const int tid = threadIdx.x;
    if (tid < BM) {
        int rr = (tid < rows) ? tid : (rows - 1);
        prow[tid] = (int)perm[s * B_ROWS + row0 + rr];
    }

    const int lane = tid & 63;
    const int wid  = tid >> 6;
    const int rsub = lane >> 2;   // row within 16-row staging group
    const int seg  = lane & 3;    // 16B segment within 64B row

    // staging addresses: wave wid stages rows [wid*32, wid*32+32)
    const unsigned short* ag0 = xq + ((size_t)(offs[s] + row0 + wid * 32 + rsub)) * K_DIM + seg * 8;
    const unsigned short* ag1 = ag0 + (size_t)16 * K_DIM;
    const unsigned short* bg0 = wt + ((size_t)s * N_DIM + n0 + wid * 32 + rsub) * K_DIM + seg * 8;
    const unsigned short* bg1 = bg0 + (size_t)16 * K_DIM;
    unsigned short* al0 = &sA[(wid * 32) * BK];
    unsigned short* al1 = &sA[(wid * 32 + 16) * BK];
    unsigned short* bl0 = &sB[(wid * 32) * BK];
    unsigned short* bl1 = &sB[(wid * 32 + 16) * BK];

    const int wm  = (wid >> 1) * 64;
    const int wn  = (wid & 1) * 64;
    const int l15 = lane & 15;
    const int quad = lane >> 4;

    f32x4 acc[4][4] = {};

    for (int ks = 0; ks < NK; ++ks) {
        gl_lds16(ag0, al0);
        gl_lds16(ag1, al1);
        gl_lds16(bg0, bl0);
        gl_lds16(bg1, bl1);
        __syncthreads();   // compiler inserts vmcnt(0) drain

        bf16x8 af[4], bfr[4];
        #pragma unroll
        for (int mt = 0; mt < 4; ++mt)
            af[mt] = *(const bf16x8*)&sA[(wm + mt * 16 + l15) * BK + quad * 8];
        #pragma unroll
        for (int nt = 0; nt < 4; ++nt)
            bfr[nt] = *(const bf16x8*)&sB[(wn + nt * 16 + l15) * BK + quad * 8];

        #pragma unroll
        for (int mt = 0; mt < 4; ++mt)
            #pragma unroll
            for (int nt = 0; nt < 4; ++nt)
                acc[mt][nt] = __builtin_amdgcn_mfma_f32_16x16x32_bf16(
                    af[mt], bfr[nt], acc[mt][nt], 0, 0, 0);

        __syncthreads();
        ag0 += BK; ag1 += BK; bg0 += BK; bg1 += BK;
    }

    float bvals[4];
    #pragma unroll
    for (int nt = 0; nt < 4; ++nt)
        bvals[nt] = bias[s * N_DIM + n0 + wn + nt * 16 + l15];

    #pragma unroll
    for (int mt = 0; mt < 4; ++mt) {
        #pragma unroll
        for (int r = 0; r < 4; ++r) {
            int rl = wm + mt * 16 + quad * 4 + r;
            if (rl < rows) {
                float* op = out + (size_t)prow[rl] * N_DIM + n0 + wn + l15;
                #pragma unroll
                for (int nt = 0; nt < 4; ++nt)
                    op[nt * 16] = acc[mt][nt][r] + bvals[nt];
            }
        }
    }
}

// ---- fallback GEMM (round-2 kernel): fp32 in, convert in-loop ----
__global__ __launch_bounds__(256, 3)
void subject_gemm_fb(const float* __restrict__ x,
                     const float* __restrict__ w,
                     const float* __restrict__ bias,
                     const int* __restrict__ cnt,
                     const int* __restrict__ tile_s,
                     const int* __restrict__ tile_m,
                     const unsigned short* __restrict__ perm,
                     float* __restrict__ out) {
    const int s = tile_s[blockIdx.x];
    if (s < 0) return;
    const int row0 = tile_m[blockIdx.x];
    const int rows = min(BM, cnt[s] - row0);
    const int n0   = blockIdx.y * BN;

    __shared__ __align__(16) unsigned short sA[BM * LDA];
    __shared__ __align__(16) unsigned short sB[BN * LDB];
    __shared__ int prow[BM];

    const int tid = threadIdx.x;
    if (tid < BM) {
        int rr = (tid < rows) ? tid : (rows - 1);
        prow[tid] = (int)perm[s * B_ROWS + row0 + rr];
    }
    __syncthreads();

    const int ar = tid >> 1;
    const int ah = tid & 1;
    const float* xp = x + (size_t)prow[ar] * K_DIM + ah * 16;
    const int bn  = tid & 127;
    const int bk2 = tid >> 7;
    const float* wp = w + (size_t)s * ((size_t)K_DIM * N_DIM)
                        + (size_t)(bk2 * 16) * N_DIM + (n0 + bn);

    const int lane = tid & 63;
    const int wid  = tid >> 6;
    const int wm   = (wid >> 1) * 64;
    const int wn   = (wid & 1) * 64;
    const int l15  = lane & 15;
    const int quad = lane >> 4;

    f32x4 acc[4][4] = {};
    f32x4 a0, a1, a2, a3;
    float bv[16];
    {
        a0 = *(const f32x4*)(xp + 0);  a1 = *(const f32x4*)(xp + 4);
        a2 = *(const f32x4*)(xp + 8);  a3 = *(const f32x4*)(xp + 12);
        #pragma unroll
        for (int i = 0; i < 16; ++i) bv[i] = wp[(size_t)i * N_DIM];
    }

    for (int ks = 0; ks < NK; ++ks) {
        u32x4 pa0 = { f2bf_pk(a0[0],a0[1]), f2bf_pk(a0[2],a0[3]),
                      f2bf_pk(a1[0],a1[1]), f2bf_pk(a1[2],a1[3]) };
        u32x4 pa1 = { f2bf_pk(a2[0],a2[1]), f2bf_pk(a2[2],a2[3]),
                      f2bf_pk(a3[0],a3[1]), f2bf_pk(a3[2],a3[3]) };
        u32x4 pb0 = { f2bf_pk(bv[0],bv[1]),   f2bf_pk(bv[2],bv[3]),
                      f2bf_pk(bv[4],bv[5]),   f2bf_pk(bv[6],bv[7]) };
        u32x4 pb1 = { f2bf_pk(bv[8],bv[9]),   f2bf_pk(bv[10],bv[11]),
                      f2bf_pk(bv[12],bv[13]), f2bf_pk(bv[14],bv[15]) };

        __syncthreads();
        *(u32x4*)&sA[ar * LDA + ah * 16 + 0] = pa0;
        *(u32x4*)&sA[ar * LDA + ah * 16 + 8] = pa1;
        *(u32x4*)&sB[bn * LDB + bk2 * 16 + 0] = pb0;
        *(u32x4*)&sB[bn * LDB + bk2 * 16 + 8] = pb1;
        __syncthreads();

        if (ks + 1 < NK) {
            const float* xq2 = xp + (ks + 1) * BK;
            a0 = *(const f32x4*)(xq2 + 0);  a1 = *(const f32x4*)(xq2 + 4);
            a2 = *(const f32x4*)(xq2 + 8);  a3 = *(const f32x4*)(xq2 + 12);
            const float* wq = wp + (size_t)((ks + 1) * BK) * N_DIM;
            #pragma unroll
            for (int i = 0; i < 16; ++i) bv[i] = wq[(size_t)i * N_DIM];
        }

        bf16x8 af[4], bfr[4];
        #pragma unroll
        for (int mt = 0; mt < 4; ++mt)
            af[mt] = *(const bf16x8*)&sA[(wm + mt * 16 + l15) * LDA + quad * 8];
        #pragma unroll
        for (int nt = 0; nt < 4; ++nt)
            bfr[nt] = *(const bf16x8*)&sB[(wn + nt * 16 + l15) * LDB + quad * 8];

        #pragma unroll
        for (int mt = 0; mt < 4; ++mt)
            #pragma unroll
            for (int nt = 0; nt < 4; ++nt)
                acc[mt][nt] = __builtin_amdgcn_mfma_f32_16x16x32_bf16(
                    af[mt], bfr[nt], acc[mt][nt], 0, 0, 0);
    }

    float bvals[4];
    #pragma unroll
    for (int nt = 0; nt < 4; ++nt)
        bvals[nt] = bias[s * N_DIM + n0 + wn + nt * 16 + l15];
    #pragma unroll
    for (int mt = 0; mt < 4; ++mt) {
        #pragma unroll
        for (int r = 0; r < 4; ++r) {
            int rl = wm + mt * 16 + quad * 4 + r;
            if (rl < rows) {
                float* op = out + (size_t)prow[rl] * N_DIM + n0 + wn + l15;
                #pragma unroll
                for (int nt = 0; nt < 4; ++nt)
                    op[nt * 16] = acc[mt][nt][r] + bvals[nt];
            }
        }
    }
}

extern "C" void kernel_launch(void* const* d_in, const int* in_sizes, int n_in,
                              void* d_out, int out_size, void* d_ws, size_t ws_size,
                              hipStream_t stream) {
    const float* x    = (const float*)d_in[0];
    const int*   sid  = (const int*)d_in[1];
    const float* w    = (const float*)d_in[2];
    const float* bias = (const float*)d_in[3];
    float* out = (float*)d_out;

    char* ws = (char*)d_ws;
    int* cnt    = (int*)(ws + WS_CNT);
    int* offs   = (int*)(ws + WS_OFFS);
    int* tile_s = (int*)(ws + WS_TILES);
    int* tile_m = (int*)(ws + WS_TILEM);
    int* rank   = (int*)(ws + WS_RANK);
    unsigned short* perm = (unsigned short*)(ws + WS_PERM);

    hipLaunchKernelGGL(zero_cnt_kernel, dim3(1), dim3(64), 0, stream, cnt);
    hipLaunchKernelGGL(bucket_kernel, dim3(B_ROWS / 256), dim3(256), 0, stream,
                       sid, cnt, perm, rank);
    hipLaunchKernelGGL(plan_kernel, dim3(1), dim3(64), 0, stream,
                       cnt, offs, tile_s, tile_m);

    if (ws_size >= WS_NEED) {
        unsigned short* xq = (unsigned short*)(ws + WS_XPERM);
        unsigned short* wt = (unsigned short*)(ws + WS_WT);
        hipLaunchKernelGGL(convert_x_kernel, dim3(B_ROWS), dim3(256), 0, stream,
                           x, sid, rank, offs, xq);
        hipLaunchKernelGGL(convert_w_kernel, dim3(K_DIM / 32, N_DIM / 128, S_NUM),
                           dim3(256), 0, stream, w, wt);
        dim3 grid(MAX_TILES, N_DIM / BN);
        hipLaunchKernelGGL(gemm_bf16_kernel, grid, dim3(256), 0, stream,
                           xq, wt, bias, cnt, offs, tile_s, tile_m, perm, out);
    } else {
        dim3 grid(MAX_TILES, N_DIM / BN);
        hipLaunchKernelGGL(subject_gemm_fb, grid, dim3(256), 0, stream,
                           x, w, bias, cnt, tile_s, tile_m, perm, out);
    }
}